// Round 5
// baseline (28339.813 us; speedup 1.0000x reference)
//
#include <hip/hip_runtime.h>
#include <math.h>

typedef __bf16 bf16_t;
typedef __bf16 bf16x8 __attribute__((ext_vector_type(8)));
typedef float f32x4 __attribute__((ext_vector_type(4)));

// ===========================================================================
// Persistent single-kernel decoder.
// Grid: 256 blocks x 256 threads (4 waves). __launch_bounds__(256,2) caps
// VGPRs at <=256 -> >=8 waves/CU capacity -> >=2 blocks/CU -> all 256 blocks
// co-resident on 256 CUs regardless of packing (deadlock-safe).
// Grid-wide sync: generation barrier, device-scope atomics + __threadfence.
// ===========================================================================

struct DecP {
    const float *hidden, *Wih0, *Whh0, *bih0, *bhh0, *Wih1, *Whh1, *bih1, *bhh1;
    const float *fc1w, *fc1b, *ln1g, *ln1b, *fc2w, *fc2b, *ln2g, *ln2b, *fc3w, *fc3b;
    float* dout;
    unsigned *barc, *barg, *barc2, *barg2;     // full + partial barrier cells
    float *h0f, *h1f, *a1r, *a2r, *b40, *b41;
    bf16_t *A0a, *A0b, *A1a, *A1b, *h1b, *a1b, *W40, *W41, *fc1wb, *fc2wb, *fc3wb;
};

// ---- grid barrier (generation protocol; cnt reset precedes gen release) ----
__device__ __forceinline__ void gbar(unsigned* cnt, unsigned* gen, unsigned nb)
{
    __syncthreads();
    if (threadIdx.x == 0) {
        __threadfence();   // release: push this CU/XCD's writes to coherence point
        unsigned g = __hip_atomic_load(gen, __ATOMIC_RELAXED, __HIP_MEMORY_SCOPE_AGENT);
        unsigned a = __hip_atomic_fetch_add(cnt, 1u, __ATOMIC_ACQ_REL, __HIP_MEMORY_SCOPE_AGENT);
        if (a == nb - 1u) {
            __hip_atomic_store(cnt, 0u, __ATOMIC_RELAXED, __HIP_MEMORY_SCOPE_AGENT);
            __hip_atomic_store(gen, g + 1u, __ATOMIC_RELEASE, __HIP_MEMORY_SCOPE_AGENT);
        } else {
            while (__hip_atomic_load(gen, __ATOMIC_ACQUIRE, __HIP_MEMORY_SCOPE_AGENT) == g)
                __builtin_amdgcn_s_sleep(2);
        }
        __threadfence();   // acquire: invalidate stale L1/L2 lines
    }
    __syncthreads();
}

// ---- 64x64 MFMA GEMM tile core (4 waves, dbuf LDS, BK=32) ------------------
// Wave wv owns rows [wv*16, wv*16+16) of the tile (R2-proven layout).
// EPI 0: C = acc + bias (fp32).  EPI 1: fused GRU combine epilogue.
template<int EPI>
__device__ __forceinline__ void gemm64(
    bf16_t (*smA)[2560], bf16_t (*smB)[2560],
    const bf16_t* __restrict__ A, const bf16_t* __restrict__ W,
    const float* __restrict__ bias, int K, int bm, int bn,
    float* __restrict__ C, int ldc,
    float* __restrict__ hf, bf16_t* __restrict__ d1, int ld1, int off1,
    bf16_t* __restrict__ d2, int ld2, int off2)
{
    const int tid = threadIdx.x;
    const int lane = tid & 63, wv = tid >> 6;
    const int quad = lane >> 4, col = lane & 15;
    const int srow = tid >> 2, sk = (tid & 3) * 8;
    const bf16_t* gA = A + (size_t)(bm + srow) * K + sk;
    const bf16_t* gW = W + (size_t)(bn + srow) * K + sk;
    const unsigned sw = srow * 40 + sk;
    const unsigned frA = (wv * 16 + col) * 40 + quad * 8;
    const unsigned frB = col * 40 + quad * 8;

    f32x4 acc[4];
#pragma unroll
    for (int j = 0; j < 4; j++)
#pragma unroll
        for (int e = 0; e < 4; e++) acc[j][e] = 0.f;

    int4 pa = *(const int4*)gA;
    int4 pb = *(const int4*)gW;
    gA += 32; gW += 32;
    *(int4*)(&smA[0][sw]) = pa;
    *(int4*)(&smB[0][sw]) = pb;
    __syncthreads();

    const int nit = K >> 5;
    for (int it = 0; it < nit; ++it) {
        const bf16_t* bA = smA[it & 1];
        const bf16_t* bB = smB[it & 1];
        if (it + 1 < nit) {
            pa = *(const int4*)gA; pb = *(const int4*)gW;
            gA += 32; gW += 32;
        }
        bf16x8 af = *(const bf16x8*)(bA + frA);
        bf16x8 b0 = *(const bf16x8*)(bB + frB);
        bf16x8 b1 = *(const bf16x8*)(bB + frB + 16 * 40);
        bf16x8 b2 = *(const bf16x8*)(bB + frB + 32 * 40);
        bf16x8 b3 = *(const bf16x8*)(bB + frB + 48 * 40);
        acc[0] = __builtin_amdgcn_mfma_f32_16x16x32_bf16(af, b0, acc[0], 0, 0, 0);
        acc[1] = __builtin_amdgcn_mfma_f32_16x16x32_bf16(af, b1, acc[1], 0, 0, 0);
        acc[2] = __builtin_amdgcn_mfma_f32_16x16x32_bf16(af, b2, acc[2], 0, 0, 0);
        acc[3] = __builtin_amdgcn_mfma_f32_16x16x32_bf16(af, b3, acc[3], 0, 0, 0);
        if (it + 1 < nit) {
            *(int4*)(&smA[(it + 1) & 1][sw]) = pa;
            *(int4*)(&smB[(it + 1) & 1][sw]) = pb;
        }
        __syncthreads();
    }

    if (EPI == 0) {
#pragma unroll
        for (int j = 0; j < 4; j++) {
            const int n = bn + j * 16 + col;
            const float bj = bias[n];
#pragma unroll
            for (int r = 0; r < 4; r++) {
                const int m = bm + wv * 16 + quad * 4 + r;
                C[(size_t)m * ldc + n] = acc[j][r] + bj;
            }
        }
    } else {
        const int cch = (bn >> 2) + col;
        const float br  = bias[bn + col];
        const float bz  = bias[bn + 16 + col];
        const float bin = bias[bn + 32 + col];
        const float bhn = bias[bn + 48 + col];
#pragma unroll
        for (int r = 0; r < 4; r++) {
            const int m = bm + wv * 16 + quad * 4 + r;
            const float gr  = acc[0][r] + br;
            const float gz  = acc[1][r] + bz;
            const float gin = acc[2][r] + bin;
            const float ghn = acc[3][r] + bhn;
            const float rr = 1.f / (1.f + __expf(-gr));
            const float zz = 1.f / (1.f + __expf(-gz));
            const float nn = tanhf(gin + rr * ghn);
            const size_t hidx = (size_t)m * 1024 + cch;
            const float hnew = (1.f - zz) * nn + zz * hf[hidx];
            hf[hidx] = hnew;
            const bf16_t hb = (bf16_t)hnew;
            d1[(size_t)m * ld1 + off1 + cch] = hb;
            d2[(size_t)m * ld2 + off2 + cch] = hb;
        }
    }
}

// ---- prep element helpers --------------------------------------------------
__device__ __forceinline__ void w4_elem(
    const float* Wih, const float* Whh, const float* bih, const float* bhh,
    bf16_t* W4, float* b4, int Kx, int q)
{
    const int K = Kx + 1024;
    const int tpr = K >> 2;
    const int np = q / tpr;
    const int k4 = (q - np * tpr) * 4;
    const int c = ((np >> 6) << 4) + (np & 15);
    const int g = (np >> 4) & 3;
    const int srow = (g == 0 ? c : (g == 1 ? 1024 + c : 2048 + c));
    float4 v = make_float4(0.f, 0.f, 0.f, 0.f);
    if (k4 < Kx) {
        if (g != 3) v = *(const float4*)(Wih + (size_t)srow * Kx + k4);
    } else {
        if (g != 2) v = *(const float4*)(Whh + (size_t)srow * 1024 + (k4 - Kx));
    }
    bf16_t* dst = W4 + (size_t)np * K + k4;
    dst[0] = (bf16_t)v.x; dst[1] = (bf16_t)v.y;
    dst[2] = (bf16_t)v.z; dst[3] = (bf16_t)v.w;
    if (k4 == 0) {
        b4[np] = (g == 0) ? bih[c] + bhh[c]
               : (g == 1) ? bih[1024 + c] + bhh[1024 + c]
               : (g == 2) ? bih[2048 + c] : bhh[2048 + c];
    }
}

__device__ __forceinline__ void cv4(const float* src, bf16_t* dst, int q)
{
    const int i4 = q * 4;
    float4 v = *(const float4*)(src + i4);
    dst[i4 + 0] = (bf16_t)v.x; dst[i4 + 1] = (bf16_t)v.y;
    dst[i4 + 2] = (bf16_t)v.z; dst[i4 + 3] = (bf16_t)v.w;
}

// ---- LN1 + GELU: wave per row (blocks 0..63, 4 rows/block) -----------------
__device__ __forceinline__ void ln1_phase(
    const float* __restrict__ X, const float* __restrict__ g,
    const float* __restrict__ b, bf16_t* __restrict__ Y)
{
    const int wv = threadIdx.x >> 6, lane = threadIdx.x & 63;
    const int row = blockIdx.x * 4 + wv;
    float v[16];
    float s = 0.f;
#pragma unroll
    for (int i = 0; i < 16; i++) {
        v[i] = X[(size_t)row * 1024 + lane + 64 * i];
        s += v[i];
    }
#pragma unroll
    for (int o = 32; o > 0; o >>= 1) s += __shfl_xor(s, o, 64);
    const float mu = s * (1.f / 1024.f);
    float s2 = 0.f;
#pragma unroll
    for (int i = 0; i < 16; i++) { float d = v[i] - mu; s2 += d * d; }
#pragma unroll
    for (int o = 32; o > 0; o >>= 1) s2 += __shfl_xor(s2, o, 64);
    const float inv = rsqrtf(s2 * (1.f / 1024.f) + 1e-5f);
#pragma unroll
    for (int i = 0; i < 16; i++) {
        const int c = lane + 64 * i;
        const float t = (v[i] - mu) * inv * g[c] + b[c];
        Y[(size_t)row * 1024 + c] = (bf16_t)(0.5f * t * (1.f + erff(t * 0.70710678118654752f)));
    }
}

// ---- head: LN2+GELU -> fc3 GEMV -> softmax (blocks 0..63, wave per row) ----
__device__ __forceinline__ void head_phase(
    const float* __restrict__ X, const float* __restrict__ lng,
    const float* __restrict__ lnb, const bf16_t* __restrict__ W,
    const float* __restrict__ bias, float* __restrict__ dout,
    bf16_t* __restrict__ a0w, int t, bf16_t* arowbase)
{
    const int wv = threadIdx.x >> 6, lane = threadIdx.x & 63;
    const int row = blockIdx.x * 4 + wv;
    bf16_t* arow = arowbase + wv * 512;          // wave-private LDS row

    float v[8];
    float s = 0.f;
#pragma unroll
    for (int i = 0; i < 8; i++) {
        v[i] = X[(size_t)row * 512 + lane + 64 * i];
        s += v[i];
    }
#pragma unroll
    for (int o = 32; o > 0; o >>= 1) s += __shfl_xor(s, o, 64);
    const float mu = s * (1.f / 512.f);
    float s2 = 0.f;
#pragma unroll
    for (int i = 0; i < 8; i++) { float d = v[i] - mu; s2 += d * d; }
#pragma unroll
    for (int o = 32; o > 0; o >>= 1) s2 += __shfl_xor(s2, o, 64);
    const float inv = rsqrtf(s2 * (1.f / 512.f) + 1e-5f);
#pragma unroll
    for (int i = 0; i < 8; i++) {
        const int c = lane + 64 * i;
        const float tt = (v[i] - mu) * inv * lng[c] + lnb[c];
        arow[c] = (bf16_t)(0.5f * tt * (1.f + erff(tt * 0.70710678118654752f)));
    }

    float acc[4];
#pragma unroll
    for (int j = 0; j < 4; j++) acc[j] = bias[lane + 64 * j];
    for (int k = 0; k < 512; k += 8) {
        bf16x8 a8 = *(const bf16x8*)(arow + k);   // wave-uniform broadcast
#pragma unroll
        for (int j = 0; j < 4; j++) {
            bf16x8 w8 = *(const bf16x8*)(W + (size_t)(lane + 64 * j) * 512 + k);
            float ss = 0.f;
#pragma unroll
            for (int e = 0; e < 8; e++) ss += (float)a8[e] * (float)w8[e];
            acc[j] += ss;
        }
    }
    float mx = fmaxf(fmaxf(acc[0], acc[1]), fmaxf(acc[2], acc[3]));
#pragma unroll
    for (int o = 32; o > 0; o >>= 1) mx = fmaxf(mx, __shfl_xor(mx, o, 64));
    float e[4], es = 0.f;
#pragma unroll
    for (int j = 0; j < 4; j++) { e[j] = expf(acc[j] - mx); es += e[j]; }
#pragma unroll
    for (int o = 32; o > 0; o >>= 1) es += __shfl_xor(es, o, 64);
    const float isum = 1.f / es;
#pragma unroll
    for (int j = 0; j < 4; j++) {
        const float pv = e[j] * isum;
        const int c = lane + 64 * j;
        dout[((size_t)row * 64 + t) * 256 + c] = pv;
        a0w[(size_t)row * 1280 + c] = (bf16_t)pv;
    }
}

// ===========================================================================
__global__ __launch_bounds__(256, 2) void decoder_all(DecP p)
{
    __shared__ __align__(16) bf16_t shA[2][2560];
    __shared__ __align__(16) bf16_t shB[2][2560];

    const int blk = blockIdx.x;
    const int gid = blk * 256 + threadIdx.x;
    const int gstr = 256 * 256;

    // ---- prep: fused weight reorder + bf16 convert + state init ----
    for (int q = gid; q < 4096 * 320; q += gstr)
        w4_elem(p.Wih0, p.Whh0, p.bih0, p.bhh0, p.W40, p.b40, 256, q);
    for (int q = gid; q < 4096 * 512; q += gstr)
        w4_elem(p.Wih1, p.Whh1, p.bih1, p.bhh1, p.W41, p.b41, 1024, q);
    for (int q = gid; q < 262144; q += gstr) cv4(p.fc1w, p.fc1wb, q);
    for (int q = gid; q < 131072; q += gstr) cv4(p.fc2w, p.fc2wb, q);
    for (int q = gid; q < 32768;  q += gstr) cv4(p.fc3w, p.fc3wb, q);
    for (int i = gid; i < 262144; i += gstr) {
        const int m = i >> 10, c = i & 1023;
        const float h0 = p.hidden[i], h1 = p.hidden[262144 + i];
        p.h0f[i] = h0; p.h1f[i] = h1;
        p.A0a[(size_t)m * 1280 + 256 + c] = (bf16_t)h0;
        p.A1a[(size_t)m * 2048 + 1024 + c] = (bf16_t)h1;
        if (c < 256) p.A0a[(size_t)m * 1280 + c] = (bf16_t)0.f;
    }

    // GRU block mapping: XCD x (= blk%8) owns n-blocks [8x, 8x+8) for L2 reuse
    const int gbn = ((blk & 7) * 8 + ((blk >> 3) & 7)) * 64;
    const int gbm = (blk >> 6) * 64;

    for (int t = 0; t < 64; ++t) {
        bf16_t* A0r = (t & 1) ? p.A0b : p.A0a;
        bf16_t* A0w = (t & 1) ? p.A0a : p.A0b;
        bf16_t* A1r = (t & 1) ? p.A1b : p.A1a;
        bf16_t* A1w = (t & 1) ? p.A1a : p.A1b;

        gbar(p.barc, p.barg, 256);   // prep (t=0) / previous step complete
        // GRU layer 0: A0r=[out|h0] -> updates h0f; bf16 h0 -> A1r[:, :1024]
        // (this step's GRU1 input) and A0w[:, 256:1280] (next step).
        gemm64<1>(shA, shB, A0r, p.W40, p.b40, 1280, gbm, gbn,
                  nullptr, 0, p.h0f, A1r, 2048, 0, A0w, 1280, 256);
        gbar(p.barc, p.barg, 256);
        // GRU layer 1: A1r=[h0_new|h1_old] -> updates h1f; bf16 h1 ->
        // A1w[:, 1024:] (next step) and h1b (fc1 input).
        gemm64<1>(shA, shB, A1r, p.W41, p.b41, 2048, gbm, gbn,
                  nullptr, 0, p.h1f, A1w, 2048, 1024, p.h1b, 1024, 0);
        gbar(p.barc, p.barg, 256);
        // FC head on blocks 0..63 only (partial barriers among 64 blocks).
        if (blk < 64) {
            gemm64<0>(shA, shB, p.h1b, p.fc1wb, p.fc1b, 1024,
                      (blk >> 4) * 64, (blk & 15) * 64, p.a1r, 1024,
                      nullptr, nullptr, 0, 0, nullptr, 0, 0);
            gbar(p.barc2, p.barg2, 64);
            ln1_phase(p.a1r, p.ln1g, p.ln1b, p.a1b);
            gbar(p.barc2, p.barg2, 64);
            if (blk < 32)
                gemm64<0>(shA, shB, p.a1b, p.fc2wb, p.fc2b, 1024,
                          (blk >> 3) * 64, (blk & 7) * 64, p.a2r, 512,
                          nullptr, nullptr, 0, 0, nullptr, 0, 0);
            gbar(p.barc2, p.barg2, 64);
            head_phase(p.a2r, p.ln2g, p.ln2b, p.fc3wb, p.fc3b,
                       p.dout, A0w, t, &shA[0][0]);
        }
    }
}

extern "C" void kernel_launch(void* const* d_in, const int* in_sizes, int n_in,
                              void* d_out, int out_size, void* d_ws, size_t ws_size,
                              hipStream_t stream)
{
    char* p = (char*)d_ws;
    auto alloc = [&](size_t bytes) { void* r = (void*)p; p += (bytes + 255) & ~(size_t)255; return r; };

    unsigned* bar = (unsigned*)alloc(256);      // barc, barg, barc2, barg2
    float*  h0f   = (float*)alloc(262144 * 4);
    float*  h1f   = (float*)alloc(262144 * 4);
    bf16_t* A0a   = (bf16_t*)alloc(256 * 1280 * 2);
    bf16_t* A0b   = (bf16_t*)alloc(256 * 1280 * 2);
    bf16_t* A1a   = (bf16_t*)alloc(256 * 2048 * 2);
    bf16_t* A1b   = (bf16_t*)alloc(256 * 2048 * 2);
    bf16_t* h1b   = (bf16_t*)alloc(262144 * 2);
    float*  a1r   = (float*)alloc(262144 * 4);
    bf16_t* a1b   = (bf16_t*)alloc(262144 * 2);
    float*  a2r   = (float*)alloc(131072 * 4);
    float*  b40   = (float*)alloc(4096 * 4);
    float*  b41   = (float*)alloc(4096 * 4);
    bf16_t* W40   = (bf16_t*)alloc((size_t)4096 * 1280 * 2);
    bf16_t* W41   = (bf16_t*)alloc((size_t)4096 * 2048 * 2);
    bf16_t* fc1wb = (bf16_t*)alloc((size_t)1048576 * 2);
    bf16_t* fc2wb = (bf16_t*)alloc((size_t)524288 * 2);
    bf16_t* fc3wb = (bf16_t*)alloc((size_t)131072 * 2);

    hipMemsetAsync(bar, 0, 256, stream);        // zero barrier cells (ws is poisoned)

    DecP prm;
    prm.hidden = (const float*)d_in[0];
    prm.Wih0 = (const float*)d_in[1];  prm.Whh0 = (const float*)d_in[2];
    prm.bih0 = (const float*)d_in[3];  prm.bhh0 = (const float*)d_in[4];
    prm.Wih1 = (const float*)d_in[5];  prm.Whh1 = (const float*)d_in[6];
    prm.bih1 = (const float*)d_in[7];  prm.bhh1 = (const float*)d_in[8];
    prm.fc1w = (const float*)d_in[9];  prm.fc1b = (const float*)d_in[10];
    prm.ln1g = (const float*)d_in[11]; prm.ln1b = (const float*)d_in[12];
    prm.fc2w = (const float*)d_in[13]; prm.fc2b = (const float*)d_in[14];
    prm.ln2g = (const float*)d_in[15]; prm.ln2b = (const float*)d_in[16];
    prm.fc3w = (const float*)d_in[17]; prm.fc3b = (const float*)d_in[18];
    prm.dout = (float*)d_out;
    prm.barc = bar; prm.barg = bar + 16; prm.barc2 = bar + 32; prm.barg2 = bar + 48;
    prm.h0f = h0f; prm.h1f = h1f; prm.a1r = a1r; prm.a2r = a2r;
    prm.b40 = b40; prm.b41 = b41;
    prm.A0a = A0a; prm.A0b = A0b; prm.A1a = A1a; prm.A1b = A1b;
    prm.h1b = h1b; prm.a1b = a1b; prm.W40 = W40; prm.W41 = W41;
    prm.fc1wb = fc1wb; prm.fc2wb = fc2wb; prm.fc3wb = fc3wb;

    decoder_all<<<256, 256, 0, stream>>>(prm);
}

// Round 6
// 8176.077 us; speedup vs baseline: 3.4662x; 3.4662x over previous
//
#include <hip/hip_runtime.h>
#include <math.h>

typedef __bf16 bf16_t;
typedef __bf16 bf16x8 __attribute__((ext_vector_type(8)));
typedef float f32x4 __attribute__((ext_vector_type(4)));

// ---------------------------------------------------------------------------
// MFMA GEMM (R2-proven core): C[M,N] = A[M,K](bf16) @ W[N,K](bf16)^T (+bias)
// Tile: (NW*16) x 64, BK=32. Wave w computes rows [w*16,w*16+16) x 64 cols.
// EPI 0: C fp32 = acc + bias.
// EPI 1: fused GRU combine epilogue (gates r,z,i_n,h_n in n-tiles j=0..3,
//        weights pre-reordered by build_w4). Updates hf, writes bf16 h to d1/d2.
// ---------------------------------------------------------------------------
template<int NW, int EPI>
__global__ __launch_bounds__(NW * 64) void gemm_mfma(
    const bf16_t* __restrict__ A, const bf16_t* __restrict__ W,
    const float* __restrict__ bias, int K,
    float* __restrict__ C, int ldc,
    float* __restrict__ hf,
    bf16_t* __restrict__ d1, int ld1, int off1,
    bf16_t* __restrict__ d2, int ld2, int off2)
{
    constexpr int MT = NW * 16;
    constexpr int R = 4 / NW;              // B-row loads per thread
    __shared__ __align__(16) bf16_t ldsA[MT * 40];
    __shared__ __align__(16) bf16_t ldsB[64 * 40];

    int bx = blockIdx.x, by = blockIdx.y;
    if (EPI == 1) {
        // grid (64,4): XCD-aware remap -> XCD x keeps its W4 slice L2-resident
        int d = by * 64 + bx;
        bx = (d & 7) * 8 + ((d >> 3) & 7);
        by = d >> 6;
    }
    const int bm = by * MT, bn = bx * 64;
    const int tid = threadIdx.x;

    const int srow = tid >> 2, schk = tid & 3;
    const bf16_t* gA = A + (size_t)(bm + srow) * K + schk * 8;
    const bf16_t* gW = W + (size_t)(bn + srow) * K + schk * 8;
    const unsigned sa = srow * 40 + schk * 8;

    const int lane = tid & 63, wv = tid >> 6;
    const int quad = lane >> 4, col = lane & 15;
    const unsigned ra_off = (wv * 16 + col) * 40 + quad * 8;
    const unsigned rb_off = col * 40 + quad * 8;

    f32x4 acc[4];
#pragma unroll
    for (int j = 0; j < 4; j++)
#pragma unroll
        for (int e = 0; e < 4; e++) acc[j][e] = 0.f;

    int4 pa, pb[R];
    pa = *(const int4*)gA;
#pragma unroll
    for (int r = 0; r < R; r++) pb[r] = *(const int4*)(gW + (size_t)(r * MT) * K);
    gA += 32; gW += 32;

    const int nch = K >> 5;
    for (int c = 0; c < nch; ++c) {
        __syncthreads();
        *(int4*)(ldsA + sa) = pa;
#pragma unroll
        for (int r = 0; r < R; r++) *(int4*)(ldsB + sa + r * MT * 40) = pb[r];
        __syncthreads();
        if (c + 1 < nch) {
            pa = *(const int4*)gA;
#pragma unroll
            for (int r = 0; r < R; r++) pb[r] = *(const int4*)(gW + (size_t)(r * MT) * K);
            gA += 32; gW += 32;
        }
        bf16x8 af = *(const bf16x8*)(ldsA + ra_off);
        bf16x8 b0 = *(const bf16x8*)(ldsB + rb_off);
        bf16x8 b1 = *(const bf16x8*)(ldsB + rb_off + 16 * 40);
        bf16x8 b2 = *(const bf16x8*)(ldsB + rb_off + 32 * 40);
        bf16x8 b3 = *(const bf16x8*)(ldsB + rb_off + 48 * 40);
        acc[0] = __builtin_amdgcn_mfma_f32_16x16x32_bf16(af, b0, acc[0], 0, 0, 0);
        acc[1] = __builtin_amdgcn_mfma_f32_16x16x32_bf16(af, b1, acc[1], 0, 0, 0);
        acc[2] = __builtin_amdgcn_mfma_f32_16x16x32_bf16(af, b2, acc[2], 0, 0, 0);
        acc[3] = __builtin_amdgcn_mfma_f32_16x16x32_bf16(af, b3, acc[3], 0, 0, 0);
    }

    if (EPI == 0) {
#pragma unroll
        for (int j = 0; j < 4; j++) {
            const int n = bn + j * 16 + col;
            const float bj = bias[n];
#pragma unroll
            for (int r = 0; r < 4; r++) {
                const int m = bm + wv * 16 + quad * 4 + r;
                C[(size_t)m * ldc + n] = acc[j][r] + bj;
            }
        }
    } else {
        const int cch = (bn >> 2) + col;
        const float br  = bias[bn + col];
        const float bz  = bias[bn + 16 + col];
        const float bin = bias[bn + 32 + col];
        const float bhn = bias[bn + 48 + col];
#pragma unroll
        for (int r = 0; r < 4; r++) {
            const int m = bm + wv * 16 + quad * 4 + r;
            const float gr  = acc[0][r] + br;
            const float gz  = acc[1][r] + bz;
            const float gin = acc[2][r] + bin;
            const float ghn = acc[3][r] + bhn;
            const float rr = 1.f / (1.f + __expf(-gr));
            const float zz = 1.f / (1.f + __expf(-gz));
            const float nn = tanhf(gin + rr * ghn);
            const size_t hidx = (size_t)m * 1024 + cch;
            const float hnew = (1.f - zz) * nn + zz * hf[hidx];
            hf[hidx] = hnew;
            const bf16_t hb = (bf16_t)hnew;
            d1[(size_t)m * ld1 + off1 + cch] = hb;
            d2[(size_t)m * ld2 + off2 + cch] = hb;
        }
    }
}

// ---------------------------------------------------------------------------
// head2: fused LN1+GELU -> fc2(MFMA) -> LN2+GELU -> fc3(MFMA) -> softmax.
// 16 blocks x 256 threads; block b owns batch rows [b*16, b*16+16).
// A-frags from LDS in the R2-proven chunked [kc][row][40] layout (<=2-way
// bank aliasing); B streamed from global (L2-resident) with reg double-buffer.
// ---------------------------------------------------------------------------
__global__ __launch_bounds__(256) void head2(
    const float* __restrict__ a1r,                 // fc1 out, fp32 [256][1024]
    const float* __restrict__ ln1g, const float* __restrict__ ln1b,
    const bf16_t* __restrict__ fc2w,               // [512][1024] bf16
    const float* __restrict__ fc2b,
    const float* __restrict__ ln2g, const float* __restrict__ ln2b,
    const bf16_t* __restrict__ fc3w,               // [256][512] bf16
    const float* __restrict__ fc3b,
    float* __restrict__ dout, bf16_t* __restrict__ a0w, int t)
{
    // LDS plan (aliased, peak 60 KB):
    //   [0,40960)        a1c: bf16 [32 kc][16 r][40]   live LN1 -> fc2 loop
    //   [0,33024)        f2o: fp32 [16 r][516]         live fc2 epi -> LN2
    //   [40960,61440)    a2c: bf16 [16 kc][16 r][40]   live LN2 -> fc3 loop
    //   [0,16640)        f3o: fp32 [16 r][260]         live fc3 epi -> softmax
    __shared__ __align__(16) char smem[61440];
    bf16_t* a1c = (bf16_t*)smem;
    float*  f2o = (float*)smem;
    bf16_t* a2c = (bf16_t*)(smem + 40960);
    float*  f3o = (float*)smem;

    const int blk = blockIdx.x;
    const int tid = threadIdx.x;
    const int lane = tid & 63, wv = tid >> 6;
    const int quad = lane >> 4, col = lane & 15;

    // ---- phase 1: LN1 + GELU (wave w handles rows w*4..w*4+3) ----
#pragma unroll
    for (int rr = 0; rr < 4; rr++) {
        const int r = wv * 4 + rr;
        const float* xrow = a1r + (size_t)(blk * 16 + r) * 1024;
        float v[16];
        float s = 0.f;
#pragma unroll
        for (int i = 0; i < 16; i++) { v[i] = xrow[lane + 64 * i]; s += v[i]; }
#pragma unroll
        for (int o = 32; o > 0; o >>= 1) s += __shfl_xor(s, o, 64);
        const float mu = s * (1.f / 1024.f);
        float s2 = 0.f;
#pragma unroll
        for (int i = 0; i < 16; i++) { float d = v[i] - mu; s2 += d * d; }
#pragma unroll
        for (int o = 32; o > 0; o >>= 1) s2 += __shfl_xor(s2, o, 64);
        const float inv = rsqrtf(s2 * (1.f / 1024.f) + 1e-5f);
#pragma unroll
        for (int i = 0; i < 16; i++) {
            const int c = lane + 64 * i;
            const float tt = (v[i] - mu) * inv * ln1g[c] + ln1b[c];
            const float gg = 0.5f * tt * (1.f + erff(tt * 0.70710678118654752f));
            a1c[(c >> 5) * 640 + r * 40 + (c & 31)] = (bf16_t)gg;
        }
    }
    __syncthreads();

    // ---- phase 2: fc2 MFMA. Wave w: n-tiles n0 = (w + 4*jj)*16, jj=0..7 ----
    {
        f32x4 acc[8];
#pragma unroll
        for (int j = 0; j < 8; j++)
#pragma unroll
            for (int e = 0; e < 4; e++) acc[j][e] = 0.f;
        const unsigned fra = col * 40 + quad * 8;        // + kc*640
        bf16x8 bb[2][8];
#pragma unroll
        for (int j = 0; j < 8; j++)
            bb[0][j] = *(const bf16x8*)(fc2w + (size_t)((wv + 4 * j) * 16 + col) * 1024 + quad * 8);
        for (int kc = 0; kc < 32; kc++) {
            const int cur = kc & 1;
            if (kc + 1 < 32) {
#pragma unroll
                for (int j = 0; j < 8; j++)
                    bb[cur ^ 1][j] = *(const bf16x8*)(fc2w + (size_t)((wv + 4 * j) * 16 + col) * 1024 + (kc + 1) * 32 + quad * 8);
            }
            bf16x8 af = *(const bf16x8*)(a1c + kc * 640 + fra);
#pragma unroll
            for (int j = 0; j < 8; j++)
                acc[j] = __builtin_amdgcn_mfma_f32_16x16x32_bf16(af, bb[cur][j], acc[j], 0, 0, 0);
        }
        __syncthreads();                                  // a1c dead; f2o region free
#pragma unroll
        for (int j = 0; j < 8; j++) {
            const int n = (wv + 4 * j) * 16 + col;
            const float bj = fc2b[n];
#pragma unroll
            for (int r = 0; r < 4; r++)
                f2o[(quad * 4 + r) * 516 + n] = acc[j][r] + bj;
        }
    }
    __syncthreads();

    // ---- phase 3: LN2 + GELU ----
#pragma unroll
    for (int rr = 0; rr < 4; rr++) {
        const int r = wv * 4 + rr;
        float v[8];
        float s = 0.f;
#pragma unroll
        for (int i = 0; i < 8; i++) { v[i] = f2o[r * 516 + lane + 64 * i]; s += v[i]; }
#pragma unroll
        for (int o = 32; o > 0; o >>= 1) s += __shfl_xor(s, o, 64);
        const float mu = s * (1.f / 512.f);
        float s2 = 0.f;
#pragma unroll
        for (int i = 0; i < 8; i++) { float d = v[i] - mu; s2 += d * d; }
#pragma unroll
        for (int o = 32; o > 0; o >>= 1) s2 += __shfl_xor(s2, o, 64);
        const float inv = rsqrtf(s2 * (1.f / 512.f) + 1e-5f);
#pragma unroll
        for (int i = 0; i < 8; i++) {
            const int c = lane + 64 * i;
            const float tt = (v[i] - mu) * inv * ln2g[c] + ln2b[c];
            const float gg = 0.5f * tt * (1.f + erff(tt * 0.70710678118654752f));
            a2c[(c >> 5) * 640 + r * 40 + (c & 31)] = (bf16_t)gg;
        }
    }
    __syncthreads();

    // ---- phase 4: fc3 MFMA. Wave w: n-tiles n0 = (w + 4*jj)*16, jj=0..3 ----
    {
        f32x4 acc[4];
#pragma unroll
        for (int j = 0; j < 4; j++)
#pragma unroll
            for (int e = 0; e < 4; e++) acc[j][e] = 0.f;
        const unsigned fra = col * 40 + quad * 8;
        bf16x8 bb[2][4];
#pragma unroll
        for (int j = 0; j < 4; j++)
            bb[0][j] = *(const bf16x8*)(fc3w + (size_t)((wv + 4 * j) * 16 + col) * 512 + quad * 8);
        for (int kc = 0; kc < 16; kc++) {
            const int cur = kc & 1;
            if (kc + 1 < 16) {
#pragma unroll
                for (int j = 0; j < 4; j++)
                    bb[cur ^ 1][j] = *(const bf16x8*)(fc3w + (size_t)((wv + 4 * j) * 16 + col) * 512 + (kc + 1) * 32 + quad * 8);
            }
            bf16x8 af = *(const bf16x8*)(a2c + kc * 640 + fra);
#pragma unroll
            for (int j = 0; j < 4; j++)
                acc[j] = __builtin_amdgcn_mfma_f32_16x16x32_bf16(af, bb[cur][j], acc[j], 0, 0, 0);
        }
        __syncthreads();                                  // f2o dead; f3o region free
#pragma unroll
        for (int j = 0; j < 4; j++) {
            const int n = (wv + 4 * j) * 16 + col;
            const float bj = fc3b[n];
#pragma unroll
            for (int r = 0; r < 4; r++)
                f3o[(quad * 4 + r) * 260 + n] = acc[j][r] + bj;
        }
    }
    __syncthreads();

    // ---- phase 5: softmax + output + feedback (wave w: rows w*4..w*4+3) ----
#pragma unroll
    for (int rr = 0; rr < 4; rr++) {
        const int r = wv * 4 + rr;
        const int grow = blk * 16 + r;
        float v[4];
#pragma unroll
        for (int j = 0; j < 4; j++) v[j] = f3o[r * 260 + lane + 64 * j];
        float mx = fmaxf(fmaxf(v[0], v[1]), fmaxf(v[2], v[3]));
#pragma unroll
        for (int o = 32; o > 0; o >>= 1) mx = fmaxf(mx, __shfl_xor(mx, o, 64));
        float e[4], es = 0.f;
#pragma unroll
        for (int j = 0; j < 4; j++) { e[j] = expf(v[j] - mx); es += e[j]; }
#pragma unroll
        for (int o = 32; o > 0; o >>= 1) es += __shfl_xor(es, o, 64);
        const float isum = 1.f / es;
#pragma unroll
        for (int j = 0; j < 4; j++) {
            const float pv = e[j] * isum;
            const int c = lane + 64 * j;
            dout[((size_t)grow * 64 + t) * 256 + c] = pv;
            a0w[(size_t)grow * 1280 + c] = (bf16_t)pv;
        }
    }
}

// ---------------------------------------------------------------------------
// Build fused GRU weight matrix W4[4096, K] (K = Kx + 1024), bf16, row order
// n' = (c>>4)*64 + g*16 + (c&15); g: 0=r, 1=z, 2=i_n (x only), 3=h_n (h only).
// ---------------------------------------------------------------------------
__global__ __launch_bounds__(256) void build_w4(
    const float* __restrict__ Wih, const float* __restrict__ Whh,
    const float* __restrict__ bih, const float* __restrict__ bhh,
    bf16_t* __restrict__ W4, float* __restrict__ b4, int Kx)
{
    const int K = Kx + 1024;
    const int tpr = K >> 2;
    const int idx = blockIdx.x * 256 + threadIdx.x;
    const int np = idx / tpr;
    const int k4 = (idx - np * tpr) * 4;
    const int c = ((np >> 6) << 4) + (np & 15);
    const int g = (np >> 4) & 3;
    const int srow = (g == 0 ? c : (g == 1 ? 1024 + c : 2048 + c));
    float4 v = make_float4(0.f, 0.f, 0.f, 0.f);
    if (k4 < Kx) {
        if (g != 3) v = *(const float4*)(Wih + (size_t)srow * Kx + k4);
    } else {
        if (g != 2) v = *(const float4*)(Whh + (size_t)srow * 1024 + (k4 - Kx));
    }
    bf16_t* dst = W4 + (size_t)np * K + k4;
    dst[0] = (bf16_t)v.x; dst[1] = (bf16_t)v.y;
    dst[2] = (bf16_t)v.z; dst[3] = (bf16_t)v.w;
    if (k4 == 0) {
        b4[np] = (g == 0) ? bih[c] + bhh[c]
               : (g == 1) ? bih[1024 + c] + bhh[1024 + c]
               : (g == 2) ? bih[2048 + c] : bhh[2048 + c];
    }
}

__global__ __launch_bounds__(256) void conv_bf16(
    const float* __restrict__ src, bf16_t* __restrict__ dst)
{
    const int i4 = (blockIdx.x * 256 + threadIdx.x) * 4;
    float4 v = *(const float4*)(src + i4);
    dst[i4 + 0] = (bf16_t)v.x; dst[i4 + 1] = (bf16_t)v.y;
    dst[i4 + 2] = (bf16_t)v.z; dst[i4 + 3] = (bf16_t)v.w;
}

__global__ __launch_bounds__(256) void init_state(
    const float* __restrict__ hidden, float* __restrict__ h0f,
    float* __restrict__ h1f, bf16_t* __restrict__ A0_0, bf16_t* __restrict__ A1_0)
{
    const int i = blockIdx.x * 256 + threadIdx.x;   // over 262144
    const int m = i >> 10, c = i & 1023;
    const float h0 = hidden[i], h1 = hidden[262144 + i];
    h0f[i] = h0; h1f[i] = h1;
    A0_0[(size_t)m * 1280 + 256 + c] = (bf16_t)h0;
    A1_0[(size_t)m * 2048 + 1024 + c] = (bf16_t)h1;
    if (c < 256) A0_0[(size_t)m * 1280 + c] = (bf16_t)0.f;
}

extern "C" void kernel_launch(void* const* d_in, const int* in_sizes, int n_in,
                              void* d_out, int out_size, void* d_ws, size_t ws_size,
                              hipStream_t stream)
{
    const float* hidden = (const float*)d_in[0];
    const float* W_ih0  = (const float*)d_in[1];
    const float* W_hh0  = (const float*)d_in[2];
    const float* b_ih0  = (const float*)d_in[3];
    const float* b_hh0  = (const float*)d_in[4];
    const float* W_ih1  = (const float*)d_in[5];
    const float* W_hh1  = (const float*)d_in[6];
    const float* b_ih1  = (const float*)d_in[7];
    const float* b_hh1  = (const float*)d_in[8];
    const float* fc1_w  = (const float*)d_in[9];
    const float* fc1_b  = (const float*)d_in[10];
    const float* ln1_g  = (const float*)d_in[11];
    const float* ln1_b  = (const float*)d_in[12];
    const float* fc2_w  = (const float*)d_in[13];
    const float* fc2_b  = (const float*)d_in[14];
    const float* ln2_g  = (const float*)d_in[15];
    const float* ln2_b  = (const float*)d_in[16];
    const float* fc3_w  = (const float*)d_in[17];
    const float* fc3_b  = (const float*)d_in[18];
    float* dout = (float*)d_out;

    char* p = (char*)d_ws;
    auto alloc = [&](size_t bytes) { void* r = (void*)p; p += (bytes + 255) & ~(size_t)255; return r; };
    float*  h0f   = (float*)alloc(262144 * 4);
    float*  h1f   = (float*)alloc(262144 * 4);
    bf16_t* A0[2] = { (bf16_t*)alloc(256 * 1280 * 2), (bf16_t*)alloc(256 * 1280 * 2) };
    bf16_t* A1[2] = { (bf16_t*)alloc(256 * 2048 * 2), (bf16_t*)alloc(256 * 2048 * 2) };
    bf16_t* h1b   = (bf16_t*)alloc(262144 * 2);
    float*  a1r   = (float*)alloc(262144 * 4);
    float*  b4_0  = (float*)alloc(4096 * 4);
    float*  b4_1  = (float*)alloc(4096 * 4);
    bf16_t* W4_0  = (bf16_t*)alloc((size_t)4096 * 1280 * 2);
    bf16_t* W4_1  = (bf16_t*)alloc((size_t)4096 * 2048 * 2);
    bf16_t* fc1wb = (bf16_t*)alloc((size_t)1048576 * 2);
    bf16_t* fc2wb = (bf16_t*)alloc((size_t)524288 * 2);
    bf16_t* fc3wb = (bf16_t*)alloc((size_t)131072 * 2);

    // weight prep (graph-safe, every call)
    build_w4<<<5120, 256, 0, stream>>>(W_ih0, W_hh0, b_ih0, b_hh0, W4_0, b4_0, 256);
    build_w4<<<8192, 256, 0, stream>>>(W_ih1, W_hh1, b_ih1, b_hh1, W4_1, b4_1, 1024);
    conv_bf16<<<1024, 256, 0, stream>>>(fc1_w, fc1wb);
    conv_bf16<<<512, 256, 0, stream>>>(fc2_w, fc2wb);
    conv_bf16<<<128, 256, 0, stream>>>(fc3_w, fc3wb);
    init_state<<<1024, 256, 0, stream>>>(hidden, h0f, h1f, A0[0], A1[0]);

    for (int t = 0; t < 64; t++) {
        bf16_t* A0r = A0[t & 1];
        bf16_t* A0w = A0[(t + 1) & 1];
        bf16_t* A1r = A1[t & 1];
        bf16_t* A1w = A1[(t + 1) & 1];

        // GRU layer 0: reads A0r=[out|h0]; updates h0f; writes bf16 h0 into
        // A1r[:, :1024] (gru1, this step) and A0w[:, 256:1280] (next step).
        gemm_mfma<4, 1><<<dim3(64, 4), 256, 0, stream>>>(
            A0r, W4_0, b4_0, 1280, nullptr, 0,
            h0f, A1r, 2048, 0, A0w, 1280, 256);
        // GRU layer 1: reads A1r=[h0_new|h1_old]; updates h1f; writes bf16 h1
        // into A1w[:, 1024:] (next step) and h1b (fc1 input).
        gemm_mfma<4, 1><<<dim3(64, 4), 256, 0, stream>>>(
            A1r, W4_1, b4_1, 2048, nullptr, 0,
            h1f, A1w, 2048, 1024, h1b, 1024, 0);
        // fc1 GEMM -> a1r fp32
        gemm_mfma<2, 0><<<dim3(16, 8), 128, 0, stream>>>(
            h1b, fc1wb, fc1_b, 1024, a1r, 1024, nullptr, nullptr, 0, 0, nullptr, 0, 0);
        // fused LN1+GELU -> fc2 -> LN2+GELU -> fc3 -> softmax -> feedback
        head2<<<16, 256, 0, stream>>>(
            a1r, ln1_g, ln1_b, fc2wb, fc2_b, ln2_g, ln2_b,
            fc3wb, fc3_b, dout, A0w, t);
    }
}